// Round 23
// baseline (309.650 us; speedup 1.0000x reference)
//
#include <hip/hip_runtime.h>

#define GG 64        // graphs
#define STRIDE 10240 // per-bin region capacity (mean 8704 -> big headroom)
#define NBINMAX 256  // bins = dst>>9, N<=131072

typedef __attribute__((ext_vector_type(8))) short short8;   // 8 bf16 (4 VGPR)
typedef __attribute__((ext_vector_type(4))) float f32x4;    // 4 fp32 acc

// ---------------- bf16 helpers ----------------

__device__ inline unsigned short bf16rne(float f) {
  unsigned int x = __float_as_uint(f);
  unsigned int r = (x + 0x7FFFu + ((x >> 16) & 1u)) >> 16;
  return (unsigned short)r;
}
__device__ inline unsigned int pack2(float a, float b) {
  return (unsigned int)bf16rne(a) | ((unsigned int)bf16rne(b) << 16);
}
__device__ inline float blo(unsigned int v) { return __uint_as_float(v << 16); }
__device__ inline float bhi(unsigned int v) { return __uint_as_float(v & 0xFFFF0000u); }

// ---------------- prep: weight split + gcur/gstart/pooled init ----------------

__global__ __launch_bounds__(256) void wprep(const float* __restrict__ w0,
                                             const float* __restrict__ w1,
                                             unsigned short* __restrict__ wt,
                                             int* __restrict__ gcur,
                                             int* __restrict__ gstart,
                                             float* __restrict__ pooled) {
  int b = blockIdx.x, t = threadIdx.x;
  if (b == 0) gcur[t] = t * STRIDE;
  if (b == 1 && t < 64) gstart[t] = -1;
  if (b >= 2 && b < 34) pooled[(b - 2) * 256 + t] = 0.f;
  int idx = b * 256 + t;   // 0..32767
  int layer = idx >> 14;
  int e = idx & 16383;
  int k = e >> 7, n = e & 127;
  float v = (layer ? w1 : w0)[e];
  unsigned short hi = bf16rne(v);
  float hif = __uint_as_float((unsigned int)hi << 16);
  unsigned short lo = bf16rne(v - hif);
  unsigned short* basep = wt + layer * 32768;
  basep[n * 128 + k] = hi;
  basep[16384 + n * 128 + k] = lo;
}

// ---------------- mega1: gemm0 (fp32 in) | part_p1 | gbounds ----------------

__global__ __launch_bounds__(512) void mega1(
    const float* __restrict__ in, const unsigned short* __restrict__ wtL,
    const float* __restrict__ att_s, const float* __restrict__ att_d,
    unsigned int* __restrict__ h16, float* __restrict__ a_s, float* __restrict__ a_d,
    const int* __restrict__ ei, int* __restrict__ gcur, unsigned int* __restrict__ pairs,
    const int* __restrict__ batch, int* __restrict__ gstart,
    int N, int E, int bG, int P1B) {
  __shared__ unsigned short xh[128][40], xl[128][40];
  __shared__ int hist[NBINMAX], gbase[NBINMAX], lcur[NBINMAX];
  int bid = blockIdx.x;
  int t = threadIdx.x;

  if (bid < bG) {
    // ================= gemm layer 0 =================
    int base = bid * 128;
    int lane = t & 63, w = t >> 6;
    int l15 = lane & 15, lg = lane >> 4;
    int hd = w & 3;
    int n0 = hd * 32;
    int rh = w >> 2;

    f32x4 zero4 = {0.f, 0.f, 0.f, 0.f};
    f32x4 acc[4][2];
    #pragma unroll
    for (int rt = 0; rt < 4; ++rt) { acc[rt][0] = zero4; acc[rt][1] = zero4; }

    int sr = t >> 2;
    int sc = (t & 3) * 8;
    int gr = base + sr;
    int rc = gr < N ? gr : (N - 1);
    const float* xpf = in + (size_t)rc * 128 + sc;

    const unsigned short* wh0 = &wtL[(size_t)(n0 + l15) * 128];
    const unsigned short* wh1 = &wtL[(size_t)(n0 + 16 + l15) * 128];

    float4 u0 = *(const float4*)(xpf + 0);
    float4 u1 = *(const float4*)(xpf + 4);
    short8 cbh0 = *(const short8*)(wh0 + lg * 8);
    short8 cbh1 = *(const short8*)(wh1 + lg * 8);
    short8 cbl0 = *(const short8*)(wh0 + 16384 + lg * 8);
    short8 cbl1 = *(const short8*)(wh1 + 16384 + lg * 8);

    #pragma unroll
    for (int kt = 0; kt < 4; ++kt) {
      if (kt) __syncthreads();
      {
        unsigned int b0 = __float_as_uint(u0.x), b1 = __float_as_uint(u0.y);
        unsigned int b2 = __float_as_uint(u0.z), b3 = __float_as_uint(u0.w);
        unsigned int b4 = __float_as_uint(u1.x), b5 = __float_as_uint(u1.y);
        unsigned int b6 = __float_as_uint(u1.z), b7 = __float_as_uint(u1.w);
        *(unsigned int*)&xh[sr][sc + 0] = __builtin_amdgcn_perm(b1, b0, 0x07060302u);
        *(unsigned int*)&xh[sr][sc + 2] = __builtin_amdgcn_perm(b3, b2, 0x07060302u);
        *(unsigned int*)&xh[sr][sc + 4] = __builtin_amdgcn_perm(b5, b4, 0x07060302u);
        *(unsigned int*)&xh[sr][sc + 6] = __builtin_amdgcn_perm(b7, b6, 0x07060302u);
        float r0 = u0.x - __uint_as_float(b0 & 0xFFFF0000u);
        float r1 = u0.y - __uint_as_float(b1 & 0xFFFF0000u);
        float r2 = u0.z - __uint_as_float(b2 & 0xFFFF0000u);
        float r3 = u0.w - __uint_as_float(b3 & 0xFFFF0000u);
        float r4 = u1.x - __uint_as_float(b4 & 0xFFFF0000u);
        float r5 = u1.y - __uint_as_float(b5 & 0xFFFF0000u);
        float r6 = u1.z - __uint_as_float(b6 & 0xFFFF0000u);
        float r7 = u1.w - __uint_as_float(b7 & 0xFFFF0000u);
        *(unsigned int*)&xl[sr][sc + 0] =
            __builtin_amdgcn_perm(__float_as_uint(r1), __float_as_uint(r0), 0x07060302u);
        *(unsigned int*)&xl[sr][sc + 2] =
            __builtin_amdgcn_perm(__float_as_uint(r3), __float_as_uint(r2), 0x07060302u);
        *(unsigned int*)&xl[sr][sc + 4] =
            __builtin_amdgcn_perm(__float_as_uint(r5), __float_as_uint(r4), 0x07060302u);
        *(unsigned int*)&xl[sr][sc + 6] =
            __builtin_amdgcn_perm(__float_as_uint(r7), __float_as_uint(r6), 0x07060302u);
      }
      __syncthreads();
      float4 v0 = u0, v1 = u1;
      short8 nbh0 = cbh0, nbh1 = cbh1, nbl0 = cbl0, nbl1 = cbl1;
      if (kt < 3) {
        int k1 = (kt + 1) * 32;
        v0 = *(const float4*)(xpf + k1);
        v1 = *(const float4*)(xpf + k1 + 4);
        nbh0 = *(const short8*)(wh0 + k1 + lg * 8);
        nbh1 = *(const short8*)(wh1 + k1 + lg * 8);
        nbl0 = *(const short8*)(wh0 + 16384 + k1 + lg * 8);
        nbl1 = *(const short8*)(wh1 + 16384 + k1 + lg * 8);
      }
      #pragma unroll
      for (int rt = 0; rt < 4; ++rt) {
        int row = rh * 64 + rt * 16 + l15;
        short8 fah = *(const short8*)&xh[row][lg * 8];
        short8 fal = *(const short8*)&xl[row][lg * 8];
        acc[rt][0] = __builtin_amdgcn_mfma_f32_16x16x32_bf16(fah, cbh0, acc[rt][0], 0, 0, 0);
        acc[rt][1] = __builtin_amdgcn_mfma_f32_16x16x32_bf16(fah, cbh1, acc[rt][1], 0, 0, 0);
        acc[rt][0] = __builtin_amdgcn_mfma_f32_16x16x32_bf16(fal, cbh0, acc[rt][0], 0, 0, 0);
        acc[rt][1] = __builtin_amdgcn_mfma_f32_16x16x32_bf16(fal, cbh1, acc[rt][1], 0, 0, 0);
        acc[rt][0] = __builtin_amdgcn_mfma_f32_16x16x32_bf16(fah, cbl0, acc[rt][0], 0, 0, 0);
        acc[rt][1] = __builtin_amdgcn_mfma_f32_16x16x32_bf16(fah, cbl1, acc[rt][1], 0, 0, 0);
      }
      u0 = v0; u1 = v1;
      cbh0 = nbh0; cbh1 = nbh1; cbl0 = nbl0; cbl1 = nbl1;
    }

    int headg = hd;
    float as0 = att_s[n0 + l15], as1 = att_s[n0 + 16 + l15];
    float ad0 = att_d[n0 + l15], ad1 = att_d[n0 + 16 + l15];
    #pragma unroll
    for (int rt = 0; rt < 4; ++rt) {
      float ps[4], pd[4];
      #pragma unroll
      for (int q = 0; q < 4; ++q) {
        float c0v = acc[rt][0][q], c1v = acc[rt][1][q];
        float pp0 = __shfl_xor(c0v, 1), pp1 = __shfl_xor(c1v, 1);
        int row = base + rh * 64 + rt * 16 + lg * 4 + q;
        if (!(l15 & 1) && row < N) {
          h16[(size_t)row * 64 + (n0 + l15) / 2]      = pack2(c0v, pp0);
          h16[(size_t)row * 64 + (n0 + 16 + l15) / 2] = pack2(c1v, pp1);
        }
        ps[q] = c0v * as0 + c1v * as1;
        pd[q] = c0v * ad0 + c1v * ad1;
      }
      #pragma unroll
      for (int m = 1; m <= 8; m <<= 1) {
        #pragma unroll
        for (int q = 0; q < 4; ++q) { ps[q] += __shfl_xor(ps[q], m); pd[q] += __shfl_xor(pd[q], m); }
      }
      if (l15 == 0) {
        #pragma unroll
        for (int q = 0; q < 4; ++q) {
          int row = base + rh * 64 + rt * 16 + lg * 4 + q;
          if (row < N) { a_s[row * 4 + headg] = ps[q]; a_d[row * 4 + headg] = pd[q]; }
        }
      }
    }
  } else if (bid < bG + P1B) {
    // ================= edge partition level 1 =================
    int tot = E + N;
    int base = (bid - bG) * 4096;
    if (t < NBINMAX) hist[t] = 0;
    __syncthreads();
    int sarr[8], darr[8];
    #pragma unroll
    for (int k = 0; k < 8; ++k) {
      int i = base + k * 512 + t;
      if (i < tot) {
        int s, d;
        if (i < E) { s = ei[i]; d = ei[E + i]; } else { s = i - E; d = s; }
        sarr[k] = s; darr[k] = d;
        atomicAdd(&hist[d >> 9], 1);
      } else darr[k] = -1;
    }
    __syncthreads();
    if (t < NBINMAX) {
      int c = hist[t];
      gbase[t] = (c > 0) ? atomicAdd(&gcur[t], c) : 0;
      lcur[t] = 0;
    }
    __syncthreads();
    #pragma unroll
    for (int k = 0; k < 8; ++k) {
      int d = darr[k];
      if (d >= 0) {
        int b = d >> 9;
        int p = gbase[b] + atomicAdd(&lcur[b], 1);
        pairs[p] = ((unsigned int)(d & 511) << 17) | (unsigned int)sarr[k];
      }
    }
  } else {
    // ================= graph boundaries =================
    int i = (bid - bG - P1B) * 512 + t;
    if (i < N) {
      int g = batch[i];
      if (i == 0 || batch[i - 1] != g) gstart[g] = i;
    }
  }
}

// ---------------- mega2: part_p2 | gfix ----------------

__global__ __launch_bounds__(256) void mega2(
    const unsigned int* __restrict__ pairs, const int* __restrict__ gcur,
    int* __restrict__ ssrc, int* __restrict__ offsets, int* __restrict__ counts,
    const int* __restrict__ gstart, int* __restrict__ go, int* __restrict__ ge,
    int N, int NBIN) {
  __shared__ int ncnt[512], ncur[512], excl_s[512];
  __shared__ int wsum[4];
  int b = blockIdx.x;
  int t = threadIdx.x;
  if (b < NBIN) {
    int pb = b * STRIDE;
    int cnt = gcur[b] - pb;
    ncnt[t] = 0; ncnt[t + 256] = 0;
    __syncthreads();
    for (int e = t; e < cnt; e += 256) {
      unsigned int v = pairs[pb + e];
      atomicAdd(&ncnt[v >> 17], 1);
    }
    __syncthreads();
    int c0 = ncnt[2 * t], c1 = ncnt[2 * t + 1];
    int ps = c0 + c1;
    int lane = t & 63, w = t >> 6;
    int x = ps;
    #pragma unroll
    for (int s = 1; s < 64; s <<= 1) { int y = __shfl_up(x, s); if (lane >= s) x += y; }
    if (lane == 63) wsum[w] = x;
    __syncthreads();
    int woff = 0;
    for (int i = 0; i < w; ++i) woff += wsum[i];
    int ep = woff + x - ps;
    excl_s[2 * t]     = ep;
    excl_s[2 * t + 1] = ep + c0;
    __syncthreads();
    int binstart = b << 9;
    for (int i = t; i < 512; i += 256) {
      ncur[i] = excl_s[i];
      int node = binstart + i;
      if (node < N) { offsets[node] = pb + excl_s[i]; counts[node] = ncnt[i]; }
    }
    __syncthreads();
    for (int e = t; e < cnt; e += 256) {
      unsigned int v = pairs[pb + e];
      int dl = v >> 17;
      int p = atomicAdd(&ncur[dl], 1);
      ssrc[pb + p] = (int)(v & 0x1FFFF);
    }
  } else if (t < 64) {
    int g = t;
    int s = gstart[g];
    int v = (s < 0) ? 0x7FFFFFFF : s;
    int suf = v;
    #pragma unroll
    for (int off = 1; off < 64; off <<= 1) {
      int x = __shfl_down(suf, off);
      if (g + off < 64) suf = min(suf, x);
    }
    int nxt = __shfl_down(suf, 1);
    if (g == 63) nxt = 0x7FFFFFFF;
    int e = nxt == 0x7FFFFFFF ? N : nxt;
    if (s < 0) { go[g] = e; ge[g] = e; }
    else       { go[g] = s; ge[g] = e; }
  }
}

// ---------------- MFMA GEMM layer 1 (bf16 input) + attn logits ----------------

__global__ __launch_bounds__(512) void gemm_bf16(
    const unsigned int* __restrict__ in, const unsigned short* __restrict__ wtL,
    const float* __restrict__ att_s, const float* __restrict__ att_d,
    unsigned int* __restrict__ h16, float* __restrict__ a_s,
    float* __restrict__ a_d, int N) {
  __shared__ unsigned short xh[128][40];
  int t = threadIdx.x;
  int base = blockIdx.x * 128;
  int lane = t & 63, w = t >> 6;
  int l15 = lane & 15, lg = lane >> 4;
  int hd = w & 3;
  int n0 = hd * 32;
  int rh = w >> 2;

  f32x4 zero4 = {0.f, 0.f, 0.f, 0.f};
  f32x4 acc[4][2];
  #pragma unroll
  for (int rt = 0; rt < 4; ++rt) { acc[rt][0] = zero4; acc[rt][1] = zero4; }

  int sr = t >> 2;
  int sc = (t & 3) * 8;
  int gr = base + sr;
  int rc = gr < N ? gr : (N - 1);
  const unsigned int* xpb = in + (size_t)rc * 64 + (sc >> 1);

  const unsigned short* wh0 = &wtL[(size_t)(n0 + l15) * 128];
  const unsigned short* wh1 = &wtL[(size_t)(n0 + 16 + l15) * 128];

  uint4 p0 = *(const uint4*)(xpb + 0);
  short8 cbh0 = *(const short8*)(wh0 + lg * 8);
  short8 cbh1 = *(const short8*)(wh1 + lg * 8);
  short8 cbl0 = *(const short8*)(wh0 + 16384 + lg * 8);
  short8 cbl1 = *(const short8*)(wh1 + 16384 + lg * 8);

  #pragma unroll
  for (int kt = 0; kt < 4; ++kt) {
    if (kt) __syncthreads();
    *(uint4*)&xh[sr][sc] = p0;
    __syncthreads();
    uint4 q0 = p0;
    short8 nbh0 = cbh0, nbh1 = cbh1, nbl0 = cbl0, nbl1 = cbl1;
    if (kt < 3) {
      int k1 = (kt + 1) * 32;
      q0 = *(const uint4*)(xpb + (k1 >> 1));
      nbh0 = *(const short8*)(wh0 + k1 + lg * 8);
      nbh1 = *(const short8*)(wh1 + k1 + lg * 8);
      nbl0 = *(const short8*)(wh0 + 16384 + k1 + lg * 8);
      nbl1 = *(const short8*)(wh1 + 16384 + k1 + lg * 8);
    }
    #pragma unroll
    for (int rt = 0; rt < 4; ++rt) {
      int row = rh * 64 + rt * 16 + l15;
      short8 fah = *(const short8*)&xh[row][lg * 8];
      acc[rt][0] = __builtin_amdgcn_mfma_f32_16x16x32_bf16(fah, cbh0, acc[rt][0], 0, 0, 0);
      acc[rt][1] = __builtin_amdgcn_mfma_f32_16x16x32_bf16(fah, cbh1, acc[rt][1], 0, 0, 0);
      acc[rt][0] = __builtin_amdgcn_mfma_f32_16x16x32_bf16(fah, cbl0, acc[rt][0], 0, 0, 0);
      acc[rt][1] = __builtin_amdgcn_mfma_f32_16x16x32_bf16(fah, cbl1, acc[rt][1], 0, 0, 0);
    }
    p0 = q0;
    cbh0 = nbh0; cbh1 = nbh1; cbl0 = nbl0; cbl1 = nbl1;
  }

  int headg = hd;
  float as0 = att_s[n0 + l15], as1 = att_s[n0 + 16 + l15];
  float ad0 = att_d[n0 + l15], ad1 = att_d[n0 + 16 + l15];
  #pragma unroll
  for (int rt = 0; rt < 4; ++rt) {
    float ps[4], pd[4];
    #pragma unroll
    for (int q = 0; q < 4; ++q) {
      float c0v = acc[rt][0][q], c1v = acc[rt][1][q];
      float pp0 = __shfl_xor(c0v, 1), pp1 = __shfl_xor(c1v, 1);
      int row = base + rh * 64 + rt * 16 + lg * 4 + q;
      if (!(l15 & 1) && row < N) {
        h16[(size_t)row * 64 + (n0 + l15) / 2]      = pack2(c0v, pp0);
        h16[(size_t)row * 64 + (n0 + 16 + l15) / 2] = pack2(c1v, pp1);
      }
      ps[q] = c0v * as0 + c1v * as1;
      pd[q] = c0v * ad0 + c1v * ad1;
    }
    #pragma unroll
    for (int m = 1; m <= 8; m <<= 1) {
      #pragma unroll
      for (int q = 0; q < 4; ++q) { ps[q] += __shfl_xor(ps[q], m); pd[q] += __shfl_xor(pd[q], m); }
    }
    if (l15 == 0) {
      #pragma unroll
      for (int q = 0; q < 4; ++q) {
        int row = base + rh * 64 + rt * 16 + lg * 4 + q;
        if (row < N) { a_s[row * 4 + headg] = ps[q]; a_d[row * 4 + headg] = pd[q]; }
      }
    }
  }
}

// ---------------- GAT aggregation: 2 nodes per wave, FUSED tails ----------------
// Peel overlaps both nodes' edges 0..15; the fused tail loop runs both
// nodes' remaining edges in lockstep (one exposed gather latency per pair
// instead of two). Predication via ex=0 with safe fallback addresses.

#define ACCP(AC, EX, V0, V1)                                                   \
  { float2 ex2 = make_float2(EX, EX);                                          \
    AC[0] += ex2 * make_float2(blo(V0.x), bhi(V0.x));                          \
    AC[1] += ex2 * make_float2(blo(V0.y), bhi(V0.y));                          \
    AC[2] += ex2 * make_float2(blo(V0.z), bhi(V0.z));                          \
    AC[3] += ex2 * make_float2(blo(V0.w), bhi(V0.w));                          \
    AC[4] += ex2 * make_float2(blo(V1.x), bhi(V1.x));                          \
    AC[5] += ex2 * make_float2(blo(V1.y), bhi(V1.y));                          \
    AC[6] += ex2 * make_float2(blo(V1.z), bhi(V1.z));                          \
    AC[7] += ex2 * make_float2(blo(V1.w), bhi(V1.w)); }

__global__ __launch_bounds__(256) void gat_aggregate(
    const unsigned int* __restrict__ h16, const float* __restrict__ a_s, const float* __restrict__ a_d,
    const int* __restrict__ offsets, const int* __restrict__ counts, const int* __restrict__ ssrc,
    const float* __restrict__ bias,
    const float* __restrict__ bn_g, const float* __restrict__ bn_b,
    const float* __restrict__ bn_m, const float* __restrict__ bn_v,
    unsigned int* __restrict__ y16, int N) {
  __shared__ float part[4][8][132];
  int wv = threadIdx.x >> 6;
  int lane = threadIdx.x & 63;
  int wid0 = blockIdx.x * 8 + wv * 2;
  int wid1 = wid0 + 1;
  if (wid0 >= N) return;
  bool v1 = wid1 < N;
  int w1c = v1 ? wid1 : 0;
  int eg = lane >> 3;          // edge group 0..7
  int j  = lane & 7;           // owns dims j*16 .. j*16+15
  int hh = j >> 1;             // head of those dims

  int off0 = offsets[wid0], cnt0 = counts[wid0];
  int off1 = offsets[w1c],  cnt1 = v1 ? counts[w1c] : 0;
  float ad0 = a_d[wid0 * 4 + hh];
  float ad1 = a_d[w1c * 4 + hh];
  int sA0 = ssrc[off0 + (eg < cnt0 ? eg : 0)];
  int sB0 = ssrc[off0 + (eg + 8 < cnt0 ? eg + 8 : 0)];
  int sA1 = ssrc[off1 + (eg < cnt1 ? eg : 0)];
  int sB1 = ssrc[off1 + (eg + 8 < cnt1 ? eg + 8 : 0)];
  float asA0 = a_s[sA0 * 4 + hh];
  float asB0 = a_s[sB0 * 4 + hh];
  float asA1 = a_s[sA1 * 4 + hh];
  float asB1 = a_s[sB1 * 4 + hh];

  float2 acc0[8] = {}, acc1[8] = {};
  float den0 = 0.f, den1 = 0.f;

  // ---- peeled iteration 0 for BOTH nodes: 8 payload loads in flight ----
  {
    const uint4* hA0 = (const uint4*)(h16 + (size_t)sA0 * 64 + j * 8);
    uint4 va0 = hA0[0], va1 = hA0[1];
    const uint4* hB0 = (const uint4*)(h16 + (size_t)sB0 * 64 + j * 8);
    uint4 vb0 = hB0[0], vb1 = hB0[1];
    const uint4* hA1 = (const uint4*)(h16 + (size_t)sA1 * 64 + j * 8);
    uint4 vc0 = hA1[0], vc1 = hA1[1];
    const uint4* hB1 = (const uint4*)(h16 + (size_t)sB1 * 64 + j * 8);
    uint4 vd0 = hB1[0], vd1 = hB1[1];
    int n00 = 16 + eg, n01 = 24 + eg;
    int t00 = ssrc[off0 + (n00 < cnt0 ? n00 : 0)];
    int t01 = ssrc[off0 + (n01 < cnt0 ? n01 : 0)];
    int t10 = ssrc[off1 + (n00 < cnt1 ? n00 : 0)];
    int t11 = ssrc[off1 + (n01 < cnt1 ? n01 : 0)];
    float u00 = a_s[t00 * 4 + hh];
    float u01 = a_s[t01 * 4 + hh];
    float u10 = a_s[t10 * 4 + hh];
    float u11 = a_s[t11 * 4 + hh];
    float e0 = asA0 + ad0; e0 = e0 > 0.f ? e0 : 0.2f * e0;
    float e1 = asB0 + ad0; e1 = e1 > 0.f ? e1 : 0.2f * e1;
    float x0 = (eg < cnt0)     ? __expf(e0) : 0.f;
    float x1 = (eg + 8 < cnt0) ? __expf(e1) : 0.f;
    den0 += x0 + x1;
    ACCP(acc0, x0, va0, va1)
    ACCP(acc0, x1, vb0, vb1)
    float e2 = asA1 + ad1; e2 = e2 > 0.f ? e2 : 0.2f * e2;
    float e3 = asB1 + ad1; e3 = e3 > 0.f ? e3 : 0.2f * e3;
    float x2 = (eg < cnt1)     ? __expf(e2) : 0.f;
    float x3 = (eg + 8 < cnt1) ? __expf(e3) : 0.f;
    den1 += x2 + x3;
    ACCP(acc1, x2, vc0, vc1)
    ACCP(acc1, x3, vd0, vd1)
    sA0 = t00; sB0 = t01; asA0 = u00; asB0 = u01;
    sA1 = t10; sB1 = t11; asA1 = u10; asB1 = u11;
  }

  // ---- FUSED tail: both nodes in lockstep, one exposed latency per iter ----
  int cmax = max(cnt0, cnt1);
  for (int i = eg + 16; i < cmax; i += 16) {
    const uint4* hA0 = (const uint4*)(h16 + (size_t)sA0 * 64 + j * 8);
    uint4 va0 = hA0[0], va1 = hA0[1];
    const uint4* hB0 = (const uint4*)(h16 + (size_t)sB0 * 64 + j * 8);
    uint4 vb0 = hB0[0], vb1 = hB0[1];
    const uint4* hA1 = (const uint4*)(h16 + (size_t)sA1 * 64 + j * 8);
    uint4 vc0 = hA1[0], vc1 = hA1[1];
    const uint4* hB1 = (const uint4*)(h16 + (size_t)sB1 * 64 + j * 8);
    uint4 vd0 = hB1[0], vd1 = hB1[1];
    int in0 = i + 16, in1 = i + 24;
    int t00 = ssrc[off0 + (in0 < cnt0 ? in0 : 0)];
    int t01 = ssrc[off0 + (in1 < cnt0 ? in1 : 0)];
    int t10 = ssrc[off1 + (in0 < cnt1 ? in0 : 0)];
    int t11 = ssrc[off1 + (in1 < cnt1 ? in1 : 0)];
    float u00 = a_s[t00 * 4 + hh];
    float u01 = a_s[t01 * 4 + hh];
    float u10 = a_s[t10 * 4 + hh];
    float u11 = a_s[t11 * 4 + hh];
    float e0 = asA0 + ad0; e0 = e0 > 0.f ? e0 : 0.2f * e0;
    float e1 = asB0 + ad0; e1 = e1 > 0.f ? e1 : 0.2f * e1;
    float x0 = (i < cnt0)     ? __expf(e0) : 0.f;
    float x1 = (i + 8 < cnt0) ? __expf(e1) : 0.f;
    den0 += x0 + x1;
    ACCP(acc0, x0, va0, va1)
    ACCP(acc0, x1, vb0, vb1)
    float e2 = asA1 + ad1; e2 = e2 > 0.f ? e2 : 0.2f * e2;
    float e3 = asB1 + ad1; e3 = e3 > 0.f ? e3 : 0.2f * e3;
    float x2 = (i < cnt1)     ? __expf(e2) : 0.f;
    float x3 = (i + 8 < cnt1) ? __expf(e3) : 0.f;
    den1 += x2 + x3;
    ACCP(acc1, x2, vc0, vc1)
    ACCP(acc1, x3, vd0, vd1)
    sA0 = t00; sB0 = t01; asA0 = u00; asB0 = u01;
    sA1 = t10; sB1 = t11; asA1 = u10; asB1 = u11;
  }

  den0 += __shfl_xor(den0, 8);
  den0 += __shfl_xor(den0, 16);
  den0 += __shfl_xor(den0, 32);
  den0 = __shfl(den0, (lane >> 4) * 2);
  den1 += __shfl_xor(den1, 8);
  den1 += __shfl_xor(den1, 16);
  den1 += __shfl_xor(den1, 32);
  den1 = __shfl(den1, (lane >> 4) * 2);

  int d = lane * 2;
  float2 bi = *(const float2*)(&bias[d]);
  float2 g2 = *(const float2*)(&bn_g[d]);
  float2 b2 = *(const float2*)(&bn_b[d]);
  float2 m2 = *(const float2*)(&bn_m[d]);
  float2 v2 = *(const float2*)(&bn_v[d]);
  float sc0 = g2.x * rsqrtf(v2.x + 1e-5f);
  float sc1 = g2.y * rsqrtf(v2.y + 1e-5f);

  float* pw = &part[wv][eg][j * 16];

  *(float4*)(pw + 0)  = make_float4(acc0[0].x, acc0[0].y, acc0[1].x, acc0[1].y);
  *(float4*)(pw + 4)  = make_float4(acc0[2].x, acc0[2].y, acc0[3].x, acc0[3].y);
  *(float4*)(pw + 8)  = make_float4(acc0[4].x, acc0[4].y, acc0[5].x, acc0[5].y);
  *(float4*)(pw + 12) = make_float4(acc0[6].x, acc0[6].y, acc0[7].x, acc0[7].y);
  asm volatile("s_waitcnt lgkmcnt(0)" ::: "memory");
  float r00 = 0.f, r01 = 0.f;
  #pragma unroll
  for (int g = 0; g < 8; ++g) {
    float2 v = *(const float2*)(&part[wv][g][d]);
    r00 += v.x; r01 += v.y;
  }
  asm volatile("s_waitcnt lgkmcnt(0)" ::: "memory");

  *(float4*)(pw + 0)  = make_float4(acc1[0].x, acc1[0].y, acc1[1].x, acc1[1].y);
  *(float4*)(pw + 4)  = make_float4(acc1[2].x, acc1[2].y, acc1[3].x, acc1[3].y);
  *(float4*)(pw + 8)  = make_float4(acc1[4].x, acc1[4].y, acc1[5].x, acc1[5].y);
  *(float4*)(pw + 12) = make_float4(acc1[6].x, acc1[6].y, acc1[7].x, acc1[7].y);
  asm volatile("s_waitcnt lgkmcnt(0)" ::: "memory");
  float r10 = 0.f, r11 = 0.f;
  #pragma unroll
  for (int g = 0; g < 8; ++g) {
    float2 v = *(const float2*)(&part[wv][g][d]);
    r10 += v.x; r11 += v.y;
  }

  {
    float inv = 1.f / (den0 + 1e-16f);
    float o0 = r00 * inv + bi.x;
    float o1 = r01 * inv + bi.y;
    o0 = fmaxf((o0 - m2.x) * sc0 + b2.x, 0.f);
    o1 = fmaxf((o1 - m2.y) * sc1 + b2.y, 0.f);
    y16[(size_t)wid0 * 64 + lane] = pack2(o0, o1);
  }
  if (v1) {
    float inv = 1.f / (den1 + 1e-16f);
    float o0 = r10 * inv + bi.x;
    float o1 = r11 * inv + bi.y;
    o0 = fmaxf((o0 - m2.x) * sc0 + b2.x, 0.f);
    o1 = fmaxf((o1 - m2.y) * sc1 + b2.y, 0.f);
    y16[(size_t)wid1 * 64 + lane] = pack2(o0, o1);
  }
}

// ---------------- global mean pool (partial) + head MLP ----------------

#define POOLP 8

__global__ __launch_bounds__(256) void pool_kernel(const unsigned int* __restrict__ y16,
                                                   const int* __restrict__ go,
                                                   const int* __restrict__ ge,
                                                   float* __restrict__ pooled) {
  int g = blockIdx.x / POOLP, p = blockIdx.x % POOLP;
  int s = go[g], e = ge[g];
  int len = e - s;
  int q0 = s + (len * p) / POOLP, q1 = s + (len * (p + 1)) / POOLP;
  int t = threadIdx.x;
  int d = t & 127, half = t >> 7;
  int du = d >> 1, dodd = d & 1;
  float acc = 0.f;
  for (int i = q0 + half; i < q1; i += 2) {
    unsigned int v = y16[(size_t)i * 64 + du];
    acc += dodd ? bhi(v) : blo(v);
  }
  __shared__ float red[256];
  red[t] = acc;
  __syncthreads();
  if (half == 0) atomicAdd(&pooled[g * 128 + d], red[d] + red[d + 128]);
}

__global__ __launch_bounds__(64) void mlp_kernel(const float* __restrict__ pooled,
                                                 const int* __restrict__ go,
                                                 const int* __restrict__ ge,
                                                 const float* __restrict__ w1,
                                                 const float* __restrict__ b1,
                                                 const float* __restrict__ w2,
                                                 const float* __restrict__ b2,
                                                 float* __restrict__ out) {
  int g = blockIdx.x, j = threadIdx.x;
  int cnt = ge[g] - go[g];
  float inv = 1.f / (float)(cnt > 1 ? cnt : 1);
  float z = b1[j];
  for (int k = 0; k < 128; ++k) z += pooled[g * 128 + k] * inv * w1[k * 64 + j];
  z = fmaxf(z, 0.f);
  float v = z * w2[j];
  #pragma unroll
  for (int m = 1; m < 64; m <<= 1) v += __shfl_xor(v, m);
  if (j == 0) out[g] = v + b2[0];
}

// ---------------- launch ----------------

extern "C" void kernel_launch(void* const* d_in, const int* in_sizes, int n_in,
                              void* d_out, int out_size, void* d_ws, size_t ws_size,
                              hipStream_t stream) {
  const float* x     = (const float*)d_in[0];
  const int*   ei    = (const int*)d_in[1];
  const int*   batch = (const int*)d_in[2];
  const float* w0    = (const float*)d_in[3];
  const float* atts0 = (const float*)d_in[4];
  const float* attd0 = (const float*)d_in[5];
  const float* bias0 = (const float*)d_in[6];
  const float* w1    = (const float*)d_in[7];
  const float* atts1 = (const float*)d_in[8];
  const float* attd1 = (const float*)d_in[9];
  const float* bias1 = (const float*)d_in[10];
  const float* bng0  = (const float*)d_in[11];
  const float* bnb0  = (const float*)d_in[12];
  const float* bnm0  = (const float*)d_in[13];
  const float* bnv0  = (const float*)d_in[14];
  const float* bng1  = (const float*)d_in[15];
  const float* bnb1  = (const float*)d_in[16];
  const float* bnm1  = (const float*)d_in[17];
  const float* bnv1  = (const float*)d_in[18];
  const float* l1w   = (const float*)d_in[19];
  const float* l1b   = (const float*)d_in[20];
  const float* l2w   = (const float*)d_in[21];
  const float* l2b   = (const float*)d_in[22];

  int N = in_sizes[2];        // batch length
  int E = in_sizes[1] / 2;    // edge_index is [2,E]
  int tot = E + N;
  int NBIN = (N + 511) / 512;

  char* p = (char*)d_ws;
  unsigned int* h16 = (unsigned int*)p; p += (size_t)N * 64 * 4;  // bf16 h payload
  unsigned int* y16 = (unsigned int*)p; p += (size_t)N * 64 * 4;  // bf16 y (inter-layer)
  float* a_s    = (float*)p; p += (size_t)N * 4 * 4;
  float* a_d    = (float*)p; p += (size_t)N * 4 * 4;
  int* counts   = (int*)p;   p += (size_t)N * 4;
  int* offsets  = (int*)p;   p += (size_t)N * 4;
  int* ssrc     = (int*)p;   p += (size_t)NBINMAX * STRIDE * 4;
  int* gcur     = (int*)p;   p += NBINMAX * 4;
  int* gstart   = (int*)p;   p += 64 * 4;
  int* go       = (int*)p;   p += 64 * 4;
  int* ge       = (int*)p;   p += 64 * 4;
  float* pooled = (float*)p; p += 64 * 128 * 4;
  unsigned short* wt = (unsigned short*)p; p += 2 * 32768 * 2;  // [2][hi/lo][n][k]
  // pairs buffer aliases y16 (25.6 MB >= 10.5 MB needed; dead before y16 written)
  unsigned int* pairs = y16;

  int bW2 = (N + 7) / 8;             // agg: 2 nodes per wave, 4 waves per block
  int bG = (N + 127) / 128;          // gemm: one block per 128-row stripe
  int P1B = (tot + 4095) / 4096;     // p1 blocks (512 thr x 8)
  int BNB = (N + 511) / 512;         // gbounds blocks (512 thr)

  wprep<<<128, 256, 0, stream>>>(w0, w1, wt, gcur, gstart, pooled);
  mega1<<<bG + P1B + BNB, 512, 0, stream>>>(x, wt, atts0, attd0, h16, a_s, a_d,
                                            ei, gcur, pairs, batch, gstart,
                                            N, E, bG, P1B);
  mega2<<<NBIN + 1, 256, 0, stream>>>(pairs, gcur, ssrc, offsets, counts,
                                      gstart, go, ge, N, NBIN);
  // layer 0 aggregation
  gat_aggregate<<<bW2, 256, 0, stream>>>(h16, a_s, a_d, offsets, counts, ssrc,
                                         bias0, bng0, bnb0, bnm0, bnv0, y16, N);
  // layer 1
  gemm_bf16<<<bG, 512, 0, stream>>>(y16, wt + 32768, atts1, attd1, h16, a_s, a_d, N);
  gat_aggregate<<<bW2, 256, 0, stream>>>(h16, a_s, a_d, offsets, counts, ssrc,
                                         bias1, bng1, bnb1, bnm1, bnv1, y16, N);
  // pool + head
  pool_kernel<<<GG * POOLP, 256, 0, stream>>>(y16, go, ge, pooled);
  mlp_kernel<<<GG, 64, 0, stream>>>(pooled, go, ge, l1w, l1b, l2w, l2b, (float*)d_out);
}

// Round 24
// 283.890 us; speedup vs baseline: 1.0907x; 1.0907x over previous
//
#include <hip/hip_runtime.h>

#define GG 64        // graphs
#define STRIDE 10240 // per-bin region capacity (mean 8704 -> big headroom)
#define NBINMAX 256  // bins = dst>>9, N<=131072

typedef __attribute__((ext_vector_type(8))) short short8;   // 8 bf16 (4 VGPR)
typedef __attribute__((ext_vector_type(4))) float f32x4;    // 4 fp32 acc

// ---------------- bf16 helpers ----------------

__device__ inline unsigned short bf16rne(float f) {
  unsigned int x = __float_as_uint(f);
  unsigned int r = (x + 0x7FFFu + ((x >> 16) & 1u)) >> 16;
  return (unsigned short)r;
}
__device__ inline unsigned int pack2(float a, float b) {
  return (unsigned int)bf16rne(a) | ((unsigned int)bf16rne(b) << 16);
}
__device__ inline float blo(unsigned int v) { return __uint_as_float(v << 16); }
__device__ inline float bhi(unsigned int v) { return __uint_as_float(v & 0xFFFF0000u); }

// ---------------- prep: weight split + gcur/gstart/pooled init ----------------

__global__ __launch_bounds__(256) void wprep(const float* __restrict__ w0,
                                             const float* __restrict__ w1,
                                             unsigned short* __restrict__ wt,
                                             int* __restrict__ gcur,
                                             int* __restrict__ gstart,
                                             float* __restrict__ pooled) {
  int b = blockIdx.x, t = threadIdx.x;
  if (b == 0) gcur[t] = t * STRIDE;
  if (b == 1 && t < 64) gstart[t] = -1;
  if (b >= 2 && b < 34) pooled[(b - 2) * 256 + t] = 0.f;
  int idx = b * 256 + t;   // 0..32767
  int layer = idx >> 14;
  int e = idx & 16383;
  int k = e >> 7, n = e & 127;
  float v = (layer ? w1 : w0)[e];
  unsigned short hi = bf16rne(v);
  float hif = __uint_as_float((unsigned int)hi << 16);
  unsigned short lo = bf16rne(v - hif);
  unsigned short* basep = wt + layer * 32768;
  basep[n * 128 + k] = hi;
  basep[16384 + n * 128 + k] = lo;
}

// ---------------- mega1: gemm0 (fp32 in) | part_p1 | gbounds ----------------

__global__ __launch_bounds__(512) void mega1(
    const float* __restrict__ in, const unsigned short* __restrict__ wtL,
    const float* __restrict__ att_s, const float* __restrict__ att_d,
    unsigned int* __restrict__ h16, float* __restrict__ a_s, float* __restrict__ a_d,
    const int* __restrict__ ei, int* __restrict__ gcur, unsigned int* __restrict__ pairs,
    const int* __restrict__ batch, int* __restrict__ gstart,
    int N, int E, int bG, int P1B) {
  __shared__ unsigned short xh[128][40], xl[128][40];
  __shared__ int hist[NBINMAX], gbase[NBINMAX], lcur[NBINMAX];
  int bid = blockIdx.x;
  int t = threadIdx.x;

  if (bid < bG) {
    // ================= gemm layer 0 =================
    int base = bid * 128;
    int lane = t & 63, w = t >> 6;
    int l15 = lane & 15, lg = lane >> 4;
    int hd = w & 3;
    int n0 = hd * 32;
    int rh = w >> 2;

    f32x4 zero4 = {0.f, 0.f, 0.f, 0.f};
    f32x4 acc[4][2];
    #pragma unroll
    for (int rt = 0; rt < 4; ++rt) { acc[rt][0] = zero4; acc[rt][1] = zero4; }

    int sr = t >> 2;
    int sc = (t & 3) * 8;
    int gr = base + sr;
    int rc = gr < N ? gr : (N - 1);
    const float* xpf = in + (size_t)rc * 128 + sc;

    const unsigned short* wh0 = &wtL[(size_t)(n0 + l15) * 128];
    const unsigned short* wh1 = &wtL[(size_t)(n0 + 16 + l15) * 128];

    float4 u0 = *(const float4*)(xpf + 0);
    float4 u1 = *(const float4*)(xpf + 4);
    short8 cbh0 = *(const short8*)(wh0 + lg * 8);
    short8 cbh1 = *(const short8*)(wh1 + lg * 8);
    short8 cbl0 = *(const short8*)(wh0 + 16384 + lg * 8);
    short8 cbl1 = *(const short8*)(wh1 + 16384 + lg * 8);

    #pragma unroll
    for (int kt = 0; kt < 4; ++kt) {
      if (kt) __syncthreads();
      {
        unsigned int b0 = __float_as_uint(u0.x), b1 = __float_as_uint(u0.y);
        unsigned int b2 = __float_as_uint(u0.z), b3 = __float_as_uint(u0.w);
        unsigned int b4 = __float_as_uint(u1.x), b5 = __float_as_uint(u1.y);
        unsigned int b6 = __float_as_uint(u1.z), b7 = __float_as_uint(u1.w);
        *(unsigned int*)&xh[sr][sc + 0] = __builtin_amdgcn_perm(b1, b0, 0x07060302u);
        *(unsigned int*)&xh[sr][sc + 2] = __builtin_amdgcn_perm(b3, b2, 0x07060302u);
        *(unsigned int*)&xh[sr][sc + 4] = __builtin_amdgcn_perm(b5, b4, 0x07060302u);
        *(unsigned int*)&xh[sr][sc + 6] = __builtin_amdgcn_perm(b7, b6, 0x07060302u);
        float r0 = u0.x - __uint_as_float(b0 & 0xFFFF0000u);
        float r1 = u0.y - __uint_as_float(b1 & 0xFFFF0000u);
        float r2 = u0.z - __uint_as_float(b2 & 0xFFFF0000u);
        float r3 = u0.w - __uint_as_float(b3 & 0xFFFF0000u);
        float r4 = u1.x - __uint_as_float(b4 & 0xFFFF0000u);
        float r5 = u1.y - __uint_as_float(b5 & 0xFFFF0000u);
        float r6 = u1.z - __uint_as_float(b6 & 0xFFFF0000u);
        float r7 = u1.w - __uint_as_float(b7 & 0xFFFF0000u);
        *(unsigned int*)&xl[sr][sc + 0] =
            __builtin_amdgcn_perm(__float_as_uint(r1), __float_as_uint(r0), 0x07060302u);
        *(unsigned int*)&xl[sr][sc + 2] =
            __builtin_amdgcn_perm(__float_as_uint(r3), __float_as_uint(r2), 0x07060302u);
        *(unsigned int*)&xl[sr][sc + 4] =
            __builtin_amdgcn_perm(__float_as_uint(r5), __float_as_uint(r4), 0x07060302u);
        *(unsigned int*)&xl[sr][sc + 6] =
            __builtin_amdgcn_perm(__float_as_uint(r7), __float_as_uint(r6), 0x07060302u);
      }
      __syncthreads();
      float4 v0 = u0, v1 = u1;
      short8 nbh0 = cbh0, nbh1 = cbh1, nbl0 = cbl0, nbl1 = cbl1;
      if (kt < 3) {
        int k1 = (kt + 1) * 32;
        v0 = *(const float4*)(xpf + k1);
        v1 = *(const float4*)(xpf + k1 + 4);
        nbh0 = *(const short8*)(wh0 + k1 + lg * 8);
        nbh1 = *(const short8*)(wh1 + k1 + lg * 8);
        nbl0 = *(const short8*)(wh0 + 16384 + k1 + lg * 8);
        nbl1 = *(const short8*)(wh1 + 16384 + k1 + lg * 8);
      }
      #pragma unroll
      for (int rt = 0; rt < 4; ++rt) {
        int row = rh * 64 + rt * 16 + l15;
        short8 fah = *(const short8*)&xh[row][lg * 8];
        short8 fal = *(const short8*)&xl[row][lg * 8];
        acc[rt][0] = __builtin_amdgcn_mfma_f32_16x16x32_bf16(fah, cbh0, acc[rt][0], 0, 0, 0);
        acc[rt][1] = __builtin_amdgcn_mfma_f32_16x16x32_bf16(fah, cbh1, acc[rt][1], 0, 0, 0);
        acc[rt][0] = __builtin_amdgcn_mfma_f32_16x16x32_bf16(fal, cbh0, acc[rt][0], 0, 0, 0);
        acc[rt][1] = __builtin_amdgcn_mfma_f32_16x16x32_bf16(fal, cbh1, acc[rt][1], 0, 0, 0);
        acc[rt][0] = __builtin_amdgcn_mfma_f32_16x16x32_bf16(fah, cbl0, acc[rt][0], 0, 0, 0);
        acc[rt][1] = __builtin_amdgcn_mfma_f32_16x16x32_bf16(fah, cbl1, acc[rt][1], 0, 0, 0);
      }
      u0 = v0; u1 = v1;
      cbh0 = nbh0; cbh1 = nbh1; cbl0 = nbl0; cbl1 = nbl1;
    }

    int headg = hd;
    float as0 = att_s[n0 + l15], as1 = att_s[n0 + 16 + l15];
    float ad0 = att_d[n0 + l15], ad1 = att_d[n0 + 16 + l15];
    #pragma unroll
    for (int rt = 0; rt < 4; ++rt) {
      float ps[4], pd[4];
      #pragma unroll
      for (int q = 0; q < 4; ++q) {
        float c0v = acc[rt][0][q], c1v = acc[rt][1][q];
        float pp0 = __shfl_xor(c0v, 1), pp1 = __shfl_xor(c1v, 1);
        int row = base + rh * 64 + rt * 16 + lg * 4 + q;
        if (!(l15 & 1) && row < N) {
          h16[(size_t)row * 64 + (n0 + l15) / 2]      = pack2(c0v, pp0);
          h16[(size_t)row * 64 + (n0 + 16 + l15) / 2] = pack2(c1v, pp1);
        }
        ps[q] = c0v * as0 + c1v * as1;
        pd[q] = c0v * ad0 + c1v * ad1;
      }
      #pragma unroll
      for (int m = 1; m <= 8; m <<= 1) {
        #pragma unroll
        for (int q = 0; q < 4; ++q) { ps[q] += __shfl_xor(ps[q], m); pd[q] += __shfl_xor(pd[q], m); }
      }
      if (l15 == 0) {
        #pragma unroll
        for (int q = 0; q < 4; ++q) {
          int row = base + rh * 64 + rt * 16 + lg * 4 + q;
          if (row < N) { a_s[row * 4 + headg] = ps[q]; a_d[row * 4 + headg] = pd[q]; }
        }
      }
    }
  } else if (bid < bG + P1B) {
    // ================= edge partition level 1 =================
    int tot = E + N;
    int base = (bid - bG) * 4096;
    if (t < NBINMAX) hist[t] = 0;
    __syncthreads();
    int sarr[8], darr[8];
    #pragma unroll
    for (int k = 0; k < 8; ++k) {
      int i = base + k * 512 + t;
      if (i < tot) {
        int s, d;
        if (i < E) { s = ei[i]; d = ei[E + i]; } else { s = i - E; d = s; }
        sarr[k] = s; darr[k] = d;
        atomicAdd(&hist[d >> 9], 1);
      } else darr[k] = -1;
    }
    __syncthreads();
    if (t < NBINMAX) {
      int c = hist[t];
      gbase[t] = (c > 0) ? atomicAdd(&gcur[t], c) : 0;
      lcur[t] = 0;
    }
    __syncthreads();
    #pragma unroll
    for (int k = 0; k < 8; ++k) {
      int d = darr[k];
      if (d >= 0) {
        int b = d >> 9;
        int p = gbase[b] + atomicAdd(&lcur[b], 1);
        pairs[p] = ((unsigned int)(d & 511) << 17) | (unsigned int)sarr[k];
      }
    }
  } else {
    // ================= graph boundaries =================
    int i = (bid - bG - P1B) * 512 + t;
    if (i < N) {
      int g = batch[i];
      if (i == 0 || batch[i - 1] != g) gstart[g] = i;
    }
  }
}

// ---------------- mega2: part_p2 | gfix ----------------

__global__ __launch_bounds__(256) void mega2(
    const unsigned int* __restrict__ pairs, const int* __restrict__ gcur,
    int* __restrict__ ssrc, int* __restrict__ offsets, int* __restrict__ counts,
    const int* __restrict__ gstart, int* __restrict__ go, int* __restrict__ ge,
    int N, int NBIN) {
  __shared__ int ncnt[512], ncur[512], excl_s[512];
  __shared__ int wsum[4];
  int b = blockIdx.x;
  int t = threadIdx.x;
  if (b < NBIN) {
    int pb = b * STRIDE;
    int cnt = gcur[b] - pb;
    ncnt[t] = 0; ncnt[t + 256] = 0;
    __syncthreads();
    for (int e = t; e < cnt; e += 256) {
      unsigned int v = pairs[pb + e];
      atomicAdd(&ncnt[v >> 17], 1);
    }
    __syncthreads();
    int c0 = ncnt[2 * t], c1 = ncnt[2 * t + 1];
    int ps = c0 + c1;
    int lane = t & 63, w = t >> 6;
    int x = ps;
    #pragma unroll
    for (int s = 1; s < 64; s <<= 1) { int y = __shfl_up(x, s); if (lane >= s) x += y; }
    if (lane == 63) wsum[w] = x;
    __syncthreads();
    int woff = 0;
    for (int i = 0; i < w; ++i) woff += wsum[i];
    int ep = woff + x - ps;
    excl_s[2 * t]     = ep;
    excl_s[2 * t + 1] = ep + c0;
    __syncthreads();
    int binstart = b << 9;
    for (int i = t; i < 512; i += 256) {
      ncur[i] = excl_s[i];
      int node = binstart + i;
      if (node < N) { offsets[node] = pb + excl_s[i]; counts[node] = ncnt[i]; }
    }
    __syncthreads();
    for (int e = t; e < cnt; e += 256) {
      unsigned int v = pairs[pb + e];
      int dl = v >> 17;
      int p = atomicAdd(&ncur[dl], 1);
      ssrc[pb + p] = (int)(v & 0x1FFFF);
    }
  } else if (t < 64) {
    int g = t;
    int s = gstart[g];
    int v = (s < 0) ? 0x7FFFFFFF : s;
    int suf = v;
    #pragma unroll
    for (int off = 1; off < 64; off <<= 1) {
      int x = __shfl_down(suf, off);
      if (g + off < 64) suf = min(suf, x);
    }
    int nxt = __shfl_down(suf, 1);
    if (g == 63) nxt = 0x7FFFFFFF;
    int e = nxt == 0x7FFFFFFF ? N : nxt;
    if (s < 0) { go[g] = e; ge[g] = e; }
    else       { go[g] = s; ge[g] = e; }
  }
}

// ---------------- MFMA GEMM layer 1 (bf16 input) + attn logits ----------------

__global__ __launch_bounds__(512) void gemm_bf16(
    const unsigned int* __restrict__ in, const unsigned short* __restrict__ wtL,
    const float* __restrict__ att_s, const float* __restrict__ att_d,
    unsigned int* __restrict__ h16, float* __restrict__ a_s,
    float* __restrict__ a_d, int N) {
  __shared__ unsigned short xh[128][40];
  int t = threadIdx.x;
  int base = blockIdx.x * 128;
  int lane = t & 63, w = t >> 6;
  int l15 = lane & 15, lg = lane >> 4;
  int hd = w & 3;
  int n0 = hd * 32;
  int rh = w >> 2;

  f32x4 zero4 = {0.f, 0.f, 0.f, 0.f};
  f32x4 acc[4][2];
  #pragma unroll
  for (int rt = 0; rt < 4; ++rt) { acc[rt][0] = zero4; acc[rt][1] = zero4; }

  int sr = t >> 2;
  int sc = (t & 3) * 8;
  int gr = base + sr;
  int rc = gr < N ? gr : (N - 1);
  const unsigned int* xpb = in + (size_t)rc * 64 + (sc >> 1);

  const unsigned short* wh0 = &wtL[(size_t)(n0 + l15) * 128];
  const unsigned short* wh1 = &wtL[(size_t)(n0 + 16 + l15) * 128];

  uint4 p0 = *(const uint4*)(xpb + 0);
  short8 cbh0 = *(const short8*)(wh0 + lg * 8);
  short8 cbh1 = *(const short8*)(wh1 + lg * 8);
  short8 cbl0 = *(const short8*)(wh0 + 16384 + lg * 8);
  short8 cbl1 = *(const short8*)(wh1 + 16384 + lg * 8);

  #pragma unroll
  for (int kt = 0; kt < 4; ++kt) {
    if (kt) __syncthreads();
    *(uint4*)&xh[sr][sc] = p0;
    __syncthreads();
    uint4 q0 = p0;
    short8 nbh0 = cbh0, nbh1 = cbh1, nbl0 = cbl0, nbl1 = cbl1;
    if (kt < 3) {
      int k1 = (kt + 1) * 32;
      q0 = *(const uint4*)(xpb + (k1 >> 1));
      nbh0 = *(const short8*)(wh0 + k1 + lg * 8);
      nbh1 = *(const short8*)(wh1 + k1 + lg * 8);
      nbl0 = *(const short8*)(wh0 + 16384 + k1 + lg * 8);
      nbl1 = *(const short8*)(wh1 + 16384 + k1 + lg * 8);
    }
    #pragma unroll
    for (int rt = 0; rt < 4; ++rt) {
      int row = rh * 64 + rt * 16 + l15;
      short8 fah = *(const short8*)&xh[row][lg * 8];
      acc[rt][0] = __builtin_amdgcn_mfma_f32_16x16x32_bf16(fah, cbh0, acc[rt][0], 0, 0, 0);
      acc[rt][1] = __builtin_amdgcn_mfma_f32_16x16x32_bf16(fah, cbh1, acc[rt][1], 0, 0, 0);
      acc[rt][0] = __builtin_amdgcn_mfma_f32_16x16x32_bf16(fah, cbl0, acc[rt][0], 0, 0, 0);
      acc[rt][1] = __builtin_amdgcn_mfma_f32_16x16x32_bf16(fah, cbl1, acc[rt][1], 0, 0, 0);
    }
    p0 = q0;
    cbh0 = nbh0; cbh1 = nbh1; cbl0 = nbl0; cbl1 = nbl1;
  }

  int headg = hd;
  float as0 = att_s[n0 + l15], as1 = att_s[n0 + 16 + l15];
  float ad0 = att_d[n0 + l15], ad1 = att_d[n0 + 16 + l15];
  #pragma unroll
  for (int rt = 0; rt < 4; ++rt) {
    float ps[4], pd[4];
    #pragma unroll
    for (int q = 0; q < 4; ++q) {
      float c0v = acc[rt][0][q], c1v = acc[rt][1][q];
      float pp0 = __shfl_xor(c0v, 1), pp1 = __shfl_xor(c1v, 1);
      int row = base + rh * 64 + rt * 16 + lg * 4 + q;
      if (!(l15 & 1) && row < N) {
        h16[(size_t)row * 64 + (n0 + l15) / 2]      = pack2(c0v, pp0);
        h16[(size_t)row * 64 + (n0 + 16 + l15) / 2] = pack2(c1v, pp1);
      }
      ps[q] = c0v * as0 + c1v * as1;
      pd[q] = c0v * ad0 + c1v * ad1;
    }
    #pragma unroll
    for (int m = 1; m <= 8; m <<= 1) {
      #pragma unroll
      for (int q = 0; q < 4; ++q) { ps[q] += __shfl_xor(ps[q], m); pd[q] += __shfl_xor(pd[q], m); }
    }
    if (l15 == 0) {
      #pragma unroll
      for (int q = 0; q < 4; ++q) {
        int row = base + rh * 64 + rt * 16 + lg * 4 + q;
        if (row < N) { a_s[row * 4 + headg] = ps[q]; a_d[row * 4 + headg] = pd[q]; }
      }
    }
  }
}

// ---------------- GAT aggregation: 2 nodes per wave (R20-proven) ----------------

#define ACCP(AC, EX, V0, V1)                                                   \
  { float2 ex2 = make_float2(EX, EX);                                          \
    AC[0] += ex2 * make_float2(blo(V0.x), bhi(V0.x));                          \
    AC[1] += ex2 * make_float2(blo(V0.y), bhi(V0.y));                          \
    AC[2] += ex2 * make_float2(blo(V0.z), bhi(V0.z));                          \
    AC[3] += ex2 * make_float2(blo(V0.w), bhi(V0.w));                          \
    AC[4] += ex2 * make_float2(blo(V1.x), bhi(V1.x));                          \
    AC[5] += ex2 * make_float2(blo(V1.y), bhi(V1.y));                          \
    AC[6] += ex2 * make_float2(blo(V1.z), bhi(V1.z));                          \
    AC[7] += ex2 * make_float2(blo(V1.w), bhi(V1.w)); }

__global__ __launch_bounds__(256) void gat_aggregate(
    const unsigned int* __restrict__ h16, const float* __restrict__ a_s, const float* __restrict__ a_d,
    const int* __restrict__ offsets, const int* __restrict__ counts, const int* __restrict__ ssrc,
    const float* __restrict__ bias,
    const float* __restrict__ bn_g, const float* __restrict__ bn_b,
    const float* __restrict__ bn_m, const float* __restrict__ bn_v,
    unsigned int* __restrict__ y16, int N) {
  __shared__ float part[4][8][132];
  int wv = threadIdx.x >> 6;
  int lane = threadIdx.x & 63;
  int wid0 = blockIdx.x * 8 + wv * 2;
  int wid1 = wid0 + 1;
  if (wid0 >= N) return;
  bool v1 = wid1 < N;
  int w1c = v1 ? wid1 : 0;
  int eg = lane >> 3;          // edge group 0..7
  int j  = lane & 7;           // owns dims j*16 .. j*16+15
  int hh = j >> 1;             // head of those dims

  int off0 = offsets[wid0], cnt0 = counts[wid0];
  int off1 = offsets[w1c],  cnt1 = v1 ? counts[w1c] : 0;
  float ad0 = a_d[wid0 * 4 + hh];
  float ad1 = a_d[w1c * 4 + hh];
  int sA0 = ssrc[off0 + (eg < cnt0 ? eg : 0)];
  int sB0 = ssrc[off0 + (eg + 8 < cnt0 ? eg + 8 : 0)];
  int sA1 = ssrc[off1 + (eg < cnt1 ? eg : 0)];
  int sB1 = ssrc[off1 + (eg + 8 < cnt1 ? eg + 8 : 0)];
  float asA0 = a_s[sA0 * 4 + hh];
  float asB0 = a_s[sB0 * 4 + hh];
  float asA1 = a_s[sA1 * 4 + hh];
  float asB1 = a_s[sB1 * 4 + hh];

  float2 acc0[8] = {}, acc1[8] = {};
  float den0 = 0.f, den1 = 0.f;

  // ---- peeled iteration 0 for BOTH nodes: 8 payload loads in flight ----
  {
    const uint4* hA0 = (const uint4*)(h16 + (size_t)sA0 * 64 + j * 8);
    uint4 va0 = hA0[0], va1 = hA0[1];
    const uint4* hB0 = (const uint4*)(h16 + (size_t)sB0 * 64 + j * 8);
    uint4 vb0 = hB0[0], vb1 = hB0[1];
    const uint4* hA1 = (const uint4*)(h16 + (size_t)sA1 * 64 + j * 8);
    uint4 vc0 = hA1[0], vc1 = hA1[1];
    const uint4* hB1 = (const uint4*)(h16 + (size_t)sB1 * 64 + j * 8);
    uint4 vd0 = hB1[0], vd1 = hB1[1];
    int n00 = 16 + eg, n01 = 24 + eg;
    int t00 = ssrc[off0 + (n00 < cnt0 ? n00 : 0)];
    int t01 = ssrc[off0 + (n01 < cnt0 ? n01 : 0)];
    int t10 = ssrc[off1 + (n00 < cnt1 ? n00 : 0)];
    int t11 = ssrc[off1 + (n01 < cnt1 ? n01 : 0)];
    float u00 = a_s[t00 * 4 + hh];
    float u01 = a_s[t01 * 4 + hh];
    float u10 = a_s[t10 * 4 + hh];
    float u11 = a_s[t11 * 4 + hh];
    float e0 = asA0 + ad0; e0 = e0 > 0.f ? e0 : 0.2f * e0;
    float e1 = asB0 + ad0; e1 = e1 > 0.f ? e1 : 0.2f * e1;
    float x0 = (eg < cnt0)     ? __expf(e0) : 0.f;
    float x1 = (eg + 8 < cnt0) ? __expf(e1) : 0.f;
    den0 += x0 + x1;
    ACCP(acc0, x0, va0, va1)
    ACCP(acc0, x1, vb0, vb1)
    float e2 = asA1 + ad1; e2 = e2 > 0.f ? e2 : 0.2f * e2;
    float e3 = asB1 + ad1; e3 = e3 > 0.f ? e3 : 0.2f * e3;
    float x2 = (eg < cnt1)     ? __expf(e2) : 0.f;
    float x3 = (eg + 8 < cnt1) ? __expf(e3) : 0.f;
    den1 += x2 + x3;
    ACCP(acc1, x2, vc0, vc1)
    ACCP(acc1, x3, vd0, vd1)
    sA0 = t00; sB0 = t01; asA0 = u00; asB0 = u01;
    sA1 = t10; sB1 = t11; asA1 = u10; asB1 = u11;
  }

  // ---- tails (sequential, R20-proven) ----
  for (int i = eg + 16; i < cnt0; i += 16) {
    const uint4* hpA = (const uint4*)(h16 + (size_t)sA0 * 64 + j * 8);
    uint4 va0 = hpA[0], va1 = hpA[1];
    const uint4* hpB = (const uint4*)(h16 + (size_t)sB0 * 64 + j * 8);
    uint4 vb0 = hpB[0], vb1 = hpB[1];
    int in0 = i + 16, in1 = i + 24;
    int snA = ssrc[off0 + (in0 < cnt0 ? in0 : 0)];
    int snB = ssrc[off0 + (in1 < cnt0 ? in1 : 0)];
    float anA = a_s[snA * 4 + hh];
    float anB = a_s[snB * 4 + hh];
    float eA = asA0 + ad0; eA = eA > 0.f ? eA : 0.2f * eA;
    float exA = __expf(eA);
    float eB = asB0 + ad0; eB = eB > 0.f ? eB : 0.2f * eB;
    float exB = ((i + 8) < cnt0) ? __expf(eB) : 0.f;
    den0 += exA + exB;
    ACCP(acc0, exA, va0, va1)
    ACCP(acc0, exB, vb0, vb1)
    sA0 = snA; sB0 = snB; asA0 = anA; asB0 = anB;
  }
  for (int i = eg + 16; i < cnt1; i += 16) {
    const uint4* hpA = (const uint4*)(h16 + (size_t)sA1 * 64 + j * 8);
    uint4 va0 = hpA[0], va1 = hpA[1];
    const uint4* hpB = (const uint4*)(h16 + (size_t)sB1 * 64 + j * 8);
    uint4 vb0 = hpB[0], vb1 = hpB[1];
    int in0 = i + 16, in1 = i + 24;
    int snA = ssrc[off1 + (in0 < cnt1 ? in0 : 0)];
    int snB = ssrc[off1 + (in1 < cnt1 ? in1 : 0)];
    float anA = a_s[snA * 4 + hh];
    float anB = a_s[snB * 4 + hh];
    float eA = asA1 + ad1; eA = eA > 0.f ? eA : 0.2f * eA;
    float exA = __expf(eA);
    float eB = asB1 + ad1; eB = eB > 0.f ? eB : 0.2f * eB;
    float exB = ((i + 8) < cnt1) ? __expf(eB) : 0.f;
    den1 += exA + exB;
    ACCP(acc1, exA, va0, va1)
    ACCP(acc1, exB, vb0, vb1)
    sA1 = snA; sB1 = snB; asA1 = anA; asB1 = anB;
  }

  den0 += __shfl_xor(den0, 8);
  den0 += __shfl_xor(den0, 16);
  den0 += __shfl_xor(den0, 32);
  den0 = __shfl(den0, (lane >> 4) * 2);
  den1 += __shfl_xor(den1, 8);
  den1 += __shfl_xor(den1, 16);
  den1 += __shfl_xor(den1, 32);
  den1 = __shfl(den1, (lane >> 4) * 2);

  int d = lane * 2;
  float2 bi = *(const float2*)(&bias[d]);
  float2 g2 = *(const float2*)(&bn_g[d]);
  float2 b2 = *(const float2*)(&bn_b[d]);
  float2 m2 = *(const float2*)(&bn_m[d]);
  float2 v2 = *(const float2*)(&bn_v[d]);
  float sc0 = g2.x * rsqrtf(v2.x + 1e-5f);
  float sc1 = g2.y * rsqrtf(v2.y + 1e-5f);

  float* pw = &part[wv][eg][j * 16];

  *(float4*)(pw + 0)  = make_float4(acc0[0].x, acc0[0].y, acc0[1].x, acc0[1].y);
  *(float4*)(pw + 4)  = make_float4(acc0[2].x, acc0[2].y, acc0[3].x, acc0[3].y);
  *(float4*)(pw + 8)  = make_float4(acc0[4].x, acc0[4].y, acc0[5].x, acc0[5].y);
  *(float4*)(pw + 12) = make_float4(acc0[6].x, acc0[6].y, acc0[7].x, acc0[7].y);
  asm volatile("s_waitcnt lgkmcnt(0)" ::: "memory");
  float r00 = 0.f, r01 = 0.f;
  #pragma unroll
  for (int g = 0; g < 8; ++g) {
    float2 v = *(const float2*)(&part[wv][g][d]);
    r00 += v.x; r01 += v.y;
  }
  asm volatile("s_waitcnt lgkmcnt(0)" ::: "memory");

  *(float4*)(pw + 0)  = make_float4(acc1[0].x, acc1[0].y, acc1[1].x, acc1[1].y);
  *(float4*)(pw + 4)  = make_float4(acc1[2].x, acc1[2].y, acc1[3].x, acc1[3].y);
  *(float4*)(pw + 8)  = make_float4(acc1[4].x, acc1[4].y, acc1[5].x, acc1[5].y);
  *(float4*)(pw + 12) = make_float4(acc1[6].x, acc1[6].y, acc1[7].x, acc1[7].y);
  asm volatile("s_waitcnt lgkmcnt(0)" ::: "memory");
  float r10 = 0.f, r11 = 0.f;
  #pragma unroll
  for (int g = 0; g < 8; ++g) {
    float2 v = *(const float2*)(&part[wv][g][d]);
    r10 += v.x; r11 += v.y;
  }

  {
    float inv = 1.f / (den0 + 1e-16f);
    float o0 = r00 * inv + bi.x;
    float o1 = r01 * inv + bi.y;
    o0 = fmaxf((o0 - m2.x) * sc0 + b2.x, 0.f);
    o1 = fmaxf((o1 - m2.y) * sc1 + b2.y, 0.f);
    y16[(size_t)wid0 * 64 + lane] = pack2(o0, o1);
  }
  if (v1) {
    float inv = 1.f / (den1 + 1e-16f);
    float o0 = r10 * inv + bi.x;
    float o1 = r11 * inv + bi.y;
    o0 = fmaxf((o0 - m2.x) * sc0 + b2.x, 0.f);
    o1 = fmaxf((o1 - m2.y) * sc1 + b2.y, 0.f);
    y16[(size_t)wid1 * 64 + lane] = pack2(o0, o1);
  }
}

// ---------------- global mean pool (partial) + head MLP ----------------

#define POOLP 8

__global__ __launch_bounds__(256) void pool_kernel(const unsigned int* __restrict__ y16,
                                                   const int* __restrict__ go,
                                                   const int* __restrict__ ge,
                                                   float* __restrict__ pooled) {
  int g = blockIdx.x / POOLP, p = blockIdx.x % POOLP;
  int s = go[g], e = ge[g];
  int len = e - s;
  int q0 = s + (len * p) / POOLP, q1 = s + (len * (p + 1)) / POOLP;
  int t = threadIdx.x;
  int d = t & 127, half = t >> 7;
  int du = d >> 1, dodd = d & 1;
  float acc = 0.f;
  for (int i = q0 + half; i < q1; i += 2) {
    unsigned int v = y16[(size_t)i * 64 + du];
    acc += dodd ? bhi(v) : blo(v);
  }
  __shared__ float red[256];
  red[t] = acc;
  __syncthreads();
  if (half == 0) atomicAdd(&pooled[g * 128 + d], red[d] + red[d + 128]);
}

__global__ __launch_bounds__(64) void mlp_kernel(const float* __restrict__ pooled,
                                                 const int* __restrict__ go,
                                                 const int* __restrict__ ge,
                                                 const float* __restrict__ w1,
                                                 const float* __restrict__ b1,
                                                 const float* __restrict__ w2,
                                                 const float* __restrict__ b2,
                                                 float* __restrict__ out) {
  int g = blockIdx.x, j = threadIdx.x;
  int cnt = ge[g] - go[g];
  float inv = 1.f / (float)(cnt > 1 ? cnt : 1);
  float z = b1[j];
  for (int k = 0; k < 128; ++k) z += pooled[g * 128 + k] * inv * w1[k * 64 + j];
  z = fmaxf(z, 0.f);
  float v = z * w2[j];
  #pragma unroll
  for (int m = 1; m < 64; m <<= 1) v += __shfl_xor(v, m);
  if (j == 0) out[g] = v + b2[0];
}

// ---------------- launch ----------------

extern "C" void kernel_launch(void* const* d_in, const int* in_sizes, int n_in,
                              void* d_out, int out_size, void* d_ws, size_t ws_size,
                              hipStream_t stream) {
  const float* x     = (const float*)d_in[0];
  const int*   ei    = (const int*)d_in[1];
  const int*   batch = (const int*)d_in[2];
  const float* w0    = (const float*)d_in[3];
  const float* atts0 = (const float*)d_in[4];
  const float* attd0 = (const float*)d_in[5];
  const float* bias0 = (const float*)d_in[6];
  const float* w1    = (const float*)d_in[7];
  const float* atts1 = (const float*)d_in[8];
  const float* attd1 = (const float*)d_in[9];
  const float* bias1 = (const float*)d_in[10];
  const float* bng0  = (const float*)d_in[11];
  const float* bnb0  = (const float*)d_in[12];
  const float* bnm0  = (const float*)d_in[13];
  const float* bnv0  = (const float*)d_in[14];
  const float* bng1  = (const float*)d_in[15];
  const float* bnb1  = (const float*)d_in[16];
  const float* bnm1  = (const float*)d_in[17];
  const float* bnv1  = (const float*)d_in[18];
  const float* l1w   = (const float*)d_in[19];
  const float* l1b   = (const float*)d_in[20];
  const float* l2w   = (const float*)d_in[21];
  const float* l2b   = (const float*)d_in[22];

  int N = in_sizes[2];        // batch length
  int E = in_sizes[1] / 2;    // edge_index is [2,E]
  int tot = E + N;
  int NBIN = (N + 511) / 512;

  char* p = (char*)d_ws;
  unsigned int* h16 = (unsigned int*)p; p += (size_t)N * 64 * 4;  // bf16 h payload
  unsigned int* y16 = (unsigned int*)p; p += (size_t)N * 64 * 4;  // bf16 y (inter-layer)
  float* a_s    = (float*)p; p += (size_t)N * 4 * 4;
  float* a_d    = (float*)p; p += (size_t)N * 4 * 4;
  int* counts   = (int*)p;   p += (size_t)N * 4;
  int* offsets  = (int*)p;   p += (size_t)N * 4;
  int* ssrc     = (int*)p;   p += (size_t)NBINMAX * STRIDE * 4;
  int* gcur     = (int*)p;   p += NBINMAX * 4;
  int* gstart   = (int*)p;   p += 64 * 4;
  int* go       = (int*)p;   p += 64 * 4;
  int* ge       = (int*)p;   p += 64 * 4;
  float* pooled = (float*)p; p += 64 * 128 * 4;
  unsigned short* wt = (unsigned short*)p; p += 2 * 32768 * 2;  // [2][hi/lo][n][k]
  // pairs buffer aliases y16 (25.6 MB >= 10.5 MB needed; dead before y16 written)
  unsigned int* pairs = y16;

  int bW2 = (N + 7) / 8;             // agg: 2 nodes per wave, 4 waves per block
  int bG = (N + 127) / 128;          // gemm: one block per 128-row stripe
  int P1B = (tot + 4095) / 4096;     // p1 blocks (512 thr x 8)
  int BNB = (N + 511) / 512;         // gbounds blocks (512 thr)

  wprep<<<128, 256, 0, stream>>>(w0, w1, wt, gcur, gstart, pooled);
  mega1<<<bG + P1B + BNB, 512, 0, stream>>>(x, wt, atts0, attd0, h16, a_s, a_d,
                                            ei, gcur, pairs, batch, gstart,
                                            N, E, bG, P1B);
  mega2<<<NBIN + 1, 256, 0, stream>>>(pairs, gcur, ssrc, offsets, counts,
                                      gstart, go, ge, N, NBIN);
  // layer 0 aggregation
  gat_aggregate<<<bW2, 256, 0, stream>>>(h16, a_s, a_d, offsets, counts, ssrc,
                                         bias0, bng0, bnb0, bnm0, bnv0, y16, N);
  // layer 1
  gemm_bf16<<<bG, 512, 0, stream>>>(y16, wt + 32768, atts1, attd1, h16, a_s, a_d, N);
  gat_aggregate<<<bW2, 256, 0, stream>>>(h16, a_s, a_d, offsets, counts, ssrc,
                                         bias1, bng1, bnb1, bnm1, bnv1, y16, N);
  // pool + head
  pool_kernel<<<GG * POOLP, 256, 0, stream>>>(y16, go, ge, pooled);
  mlp_kernel<<<GG, 64, 0, stream>>>(pooled, go, ge, l1w, l1b, l2w, l2b, (float*)d_out);
}